// Round 6
// baseline (213.223 us; speedup 1.0000x reference)
//
#include <hip/hip_runtime.h>
#include <hip/hip_bf16.h>

// vMF expected-likelihood loss, MI355X gfx950. Shapes hardcoded: B=2048,
// C=16384, D=128.
// prepF: normalize FEATURE rows -> bf16 fragment-swizzled swF, k1=1/unc,
//        zero d_out accumulator.
// main:  grid (C/64=256, YS=4). Block OWNS 64 classes: normalizes fp32 W rows
//        in-kernel (one-time LDS round-trip) -> register-resident A-fragments
//        + per-class consts. Loop over its 512-row slice in 32-row chunks:
//        prefetched B-fragments/k1/y -> 8 MFMA -> packed-f32 poly epilogue ->
//        fixed-shift sum of exp2 -> quad-fold -> DIRECT coalesced store to a
//        private partial row (no atomics, no LDS, no barriers in the loop).
// finish: 128 blocks reduce partial[1024][2048] per row, row loss =
//        ln2*(log2(sum)-z_y), block-reduce, one atomicAdd per block to d_out.
//
// Math: f(kappa)=63*ln(63+s)+0.5*ln(s)-s, s=sqrt(63^2+kappa^2); per-row f(k1)
// and all additive constants cancel in (-gathered + lse). F(s)=
// 63*log2(63+s)+0.5*log2(s)-log2e*s approx on s in [85,185] by deg-4 poly in
// t=0.02s-2.7 (max err ~1.4e-2 log2 => ~0.01 nats; threshold 0.195).
// |z| bounded (~40) so fp32 Sum exp2(z) cannot overflow: no max tracking.

typedef __bf16 bf16;
typedef __attribute__((ext_vector_type(8))) __bf16 bf16x8;
typedef __attribute__((ext_vector_type(4))) float f32x4;
typedef __attribute__((ext_vector_type(2))) float f32x2;

#define LOG2E 1.44269504088896340736f
#define LN2   0.69314718055994530942f
#define VNU   63.0f
#define VSQ   3969.0f

#if __has_builtin(__builtin_amdgcn_exp2f)
#define EXP2F(x) __builtin_amdgcn_exp2f(x)
#else
#define EXP2F(x) exp2f(x)
#endif
#if __has_builtin(__builtin_amdgcn_sqrtf)
#define SQRTF(x) __builtin_amdgcn_sqrtf(x)
#else
#define SQRTF(x) sqrtf(x)
#endif
#if __has_builtin(__builtin_amdgcn_logf)   /* v_log_f32 = log2 */
#define LOG2F(x) __builtin_amdgcn_logf(x)
#else
#define LOG2F(x) __log2f(x)
#endif

// F(s) poly in t = 0.02*s - 2.7 (deg 4)
#define QC0  289.4379f
#define QC1  -48.9193f
#define QC2  -2.9400f
#define QC3  0.51653f
#define QC4  -0.11373f

// ---------------- prepF: features + k1 + zero out ---------------------------
__global__ __launch_bounds__(256) void vmf_prepF(
    const float* __restrict__ feat, const float* __restrict__ unc,
    bf16* __restrict__ swF, float* __restrict__ k1,
    float* __restrict__ out0, int B)
{
  if (blockIdx.x == 0 && threadIdx.x == 0) out0[0] = 0.0f;
  const int lane = threadIdx.x & 63;
  const int b    = blockIdx.x * 4 + (threadIdx.x >> 6);
  if (b >= B) return;
  float2 xv = reinterpret_cast<const float2*>(feat + (size_t)b * 128)[lane];
  float ssq = fmaf(xv.x, xv.x, xv.y * xv.y);
  #pragma unroll
  for (int off = 32; off; off >>= 1) ssq += __shfl_xor(ssq, off);
  float inv = 1.0f / fmaxf(sqrtf(ssq), 1e-12f);
  __hip_bfloat162 hv = __float22bfloat162_rn(make_float2(xv.x * inv, xv.y * inv));
  // fragment swizzle: lane holds elements d = 2*lane, 2*lane+1
  const int t   = b >> 4;
  const int l15 = b & 15;
  const int kk  = lane >> 4;
  const int qq  = (lane >> 2) & 3;
  const int j   = 2 * (lane & 3);
  const size_t eoff = (((size_t)(t * 4 + kk)) * 64 + qq * 16 + l15) * 8 + j;
  *reinterpret_cast<__hip_bfloat162*>(swF + eoff) = hv;
  if (lane == 0) k1[b] = 1.0f / unc[b];
}

// ---------------- main ------------------------------------------------------
__global__ __launch_bounds__(256, 4) void vmf_main(
    const float* __restrict__ W, const bf16* __restrict__ swF,
    const float* __restrict__ k1a, const int* __restrict__ yy,
    float* __restrict__ partial, float* __restrict__ g2)
{
  __shared__ bf16   ldsA[4][2048];   // per-wave A-tile in fragment layout
  __shared__ float4 ldsC[64];        // per-class consts {2k2, k2^2+VSQ, f2l}

  const int lane = threadIdx.x & 63;
  const int wave = threadIdx.x >> 6;
  const int q    = lane >> 4;
  const int l15  = lane & 15;
  const int bx   = blockIdx.x;

  // ---- one-time in-kernel class prep: 16 classes/wave, 1 row per 4 lanes --
  {
    const int r16 = lane >> 2;
    const int p   = lane & 3;
    const int gc  = bx * 64 + wave * 16 + r16;
    const float4* wp = reinterpret_cast<const float4*>(W + (size_t)gc * 128 + p * 32);
    float4 xv[8];
    float ssq = 0.f;
    #pragma unroll
    for (int i = 0; i < 8; ++i) {
      xv[i] = wp[i];
      ssq += xv[i].x * xv[i].x + xv[i].y * xv[i].y +
             xv[i].z * xv[i].z + xv[i].w * xv[i].w;
    }
    ssq += __shfl_xor(ssq, 1);
    ssq += __shfl_xor(ssq, 2);
    float norm = sqrtf(ssq);
    float inv  = 1.0f / fmaxf(norm, 1e-12f);
    #pragma unroll
    for (int q2 = 0; q2 < 4; ++q2) {
      float4 a = xv[2 * q2], c = xv[2 * q2 + 1];
      __hip_bfloat162 h[4] = {
        __float22bfloat162_rn(make_float2(a.x * inv, a.y * inv)),
        __float22bfloat162_rn(make_float2(a.z * inv, a.w * inv)),
        __float22bfloat162_rn(make_float2(c.x * inv, c.y * inv)),
        __float22bfloat162_rn(make_float2(c.z * inv, c.w * inv))};
      *reinterpret_cast<bf16x8*>(&ldsA[wave][(p * 64 + q2 * 16 + r16) * 8]) =
          *reinterpret_cast<bf16x8*>(h);
    }
    if (p == 0) {
      float kap = fmaxf(norm, 1.0f) * 10.0f;
      float s2  = sqrtf(fmaf(kap, kap, VSQ));
      float f2l = fmaf(VNU, LOG2F(VNU + s2), 0.5f * LOG2F(s2)) - LOG2E * s2;
      ldsC[wave * 16 + r16] = make_float4(2.0f * kap, fmaf(kap, kap, VSQ), f2l, 0.0f);
    }
  }
  __syncthreads();

  // register-resident A fragments + class consts
  bf16x8 af[4];
  #pragma unroll
  for (int kk = 0; kk < 4; ++kk)
    af[kk] = *reinterpret_cast<bf16x8*>(&ldsA[wave][(kk * 64 + lane) * 8]);
  const int cls_base = bx * 64 + wave * 16 + q * 4;
  f32x2 cvx[4], cvy[4], cvz[4];
  #pragma unroll
  for (int r = 0; r < 4; ++r) {
    float4 c = ldsC[wave * 16 + q * 4 + r];
    cvx[r] = (f32x2){c.x, c.x};
    cvy[r] = (f32x2){c.y, c.y};
    cvz[r] = (f32x2){c.z, c.z};
  }

  // ---- batch loop: 16 chunks x 32 rows, everything prefetched 1 ahead -----
  const int rowbase = (int)blockIdx.y << 9;          // NR = 512
  const int pbase   = (bx * 4 + wave) * 2048;        // private partial row
  int rt = rowbase >> 4;
  bf16x8 bfr[2][4], bfn[2][4];
  #pragma unroll
  for (int tl = 0; tl < 2; ++tl)
    #pragma unroll
    for (int kk = 0; kk < 4; ++kk)
      bfr[tl][kk] = *reinterpret_cast<const bf16x8*>(
          swF + (((size_t)(rt + tl) * 4 + kk) * 64 + lane) * 8);
  float k10 = k1a[rowbase + l15], k11 = k1a[rowbase + 16 + l15];
  int   yv0 = yy[rowbase + l15],  yv1 = yy[rowbase + 16 + l15];

  #pragma unroll 2
  for (int ch = 0; ch < 16; ++ch) {
    const int row0 = rowbase + ch * 32 + l15;
    float k10n = 0.f, k11n = 0.f;
    int   yv0n = 0,   yv1n = 0;
    if (ch + 1 < 16) {
      const int tn = rt + 2;
      #pragma unroll
      for (int tl = 0; tl < 2; ++tl)
        #pragma unroll
        for (int kk = 0; kk < 4; ++kk)
          bfn[tl][kk] = *reinterpret_cast<const bf16x8*>(
              swF + (((size_t)(tn + tl) * 4 + kk) * 64 + lane) * 8);
      k10n = k1a[row0 + 32]; k11n = k1a[row0 + 48];
      yv0n = yy[row0 + 32];  yv1n = yy[row0 + 48];
    }

    f32x4 acc0 = {0.f, 0.f, 0.f, 0.f};
    f32x4 acc1 = {0.f, 0.f, 0.f, 0.f};
    #pragma unroll
    for (int kk = 0; kk < 4; ++kk) {
      acc0 = __builtin_amdgcn_mfma_f32_16x16x32_bf16(af[kk], bfr[0][kk], acc0, 0, 0, 0);
      acc1 = __builtin_amdgcn_mfma_f32_16x16x32_bf16(af[kk], bfr[1][kk], acc1, 0, 0, 0);
    }

    const f32x2 k1pk   = {k10, k11};
    const f32x2 k1sqpk = k1pk * k1pk;
    f32x2 z[4];
    f32x2 sum = {0.f, 0.f};
    #pragma unroll
    for (int r = 0; r < 4; ++r) {
      f32x2 acc2 = {acc0[r], acc1[r]};
      f32x2 u = __builtin_elementwise_fma(cvx[r] * k1pk, acc2, k1sqpk + cvy[r]);
      u = __builtin_elementwise_max(u, (f32x2){VSQ, VSQ});
      f32x2 s3 = {SQRTF(u.x), SQRTF(u.y)};
      f32x2 t  = __builtin_elementwise_fma((f32x2){0.02f, 0.02f}, s3,
                                           (f32x2){-2.7f, -2.7f});
      f32x2 p  = __builtin_elementwise_fma(t, (f32x2){QC4, QC4}, (f32x2){QC3, QC3});
      p = __builtin_elementwise_fma(t, p, (f32x2){QC2, QC2});
      p = __builtin_elementwise_fma(t, p, (f32x2){QC1, QC1});
      p = __builtin_elementwise_fma(t, p, (f32x2){QC0, QC0});
      z[r] = cvz[r] - p;
      sum += (f32x2){EXP2F(z[r].x), EXP2F(z[r].y)};
    }
    // gathered term: exactly one (bx, wave, q, r) matches per row
    if ((yv0 & ~3) == cls_base) {
      int rr = yv0 - cls_base;
      float zz = rr == 0 ? z[0].x : rr == 1 ? z[1].x : rr == 2 ? z[2].x : z[3].x;
      g2[row0] = zz;
    }
    if ((yv1 & ~3) == cls_base) {
      int rr = yv1 - cls_base;
      float zz = rr == 0 ? z[0].y : rr == 1 ? z[1].y : rr == 2 ? z[2].y : z[3].y;
      g2[row0 + 16] = zz;
    }
    // fold quads (16 classes) -> per-row partial; direct coalesced store
    sum.x += __shfl_xor(sum.x, 16); sum.x += __shfl_xor(sum.x, 32);
    sum.y += __shfl_xor(sum.y, 16); sum.y += __shfl_xor(sum.y, 32);
    if (q == 0) {
      partial[pbase + row0]      = sum.x;
      partial[pbase + row0 + 16] = sum.y;
    }
    #pragma unroll
    for (int tl = 0; tl < 2; ++tl)
      #pragma unroll
      for (int kk = 0; kk < 4; ++kk) bfr[tl][kk] = bfn[tl][kk];
    k10 = k10n; k11 = k11n; yv0 = yv0n; yv1 = yv1n;
    rt += 2;
  }
}

// ---------------- finish: reduce partial matrix -> mean loss ----------------
// grid 128 blocks x 256 threads; block owns 16 rows; thread = rl*16 + jt.
__global__ __launch_bounds__(256) void vmf_finish(
    const float* __restrict__ partial, const float* __restrict__ g2,
    float* __restrict__ out)
{
  const int tid = threadIdx.x;
  const int jt  = tid & 15;
  const int rl  = tid >> 4;
  const int row = blockIdx.x * 16 + rl;
  float s = 0.f;
  #pragma unroll 8
  for (int i = 0; i < 64; ++i)
    s += partial[(size_t)(jt + 16 * i) * 2048 + row];
  // reduce over jt (low 4 lane bits)
  s += __shfl_xor(s, 1);
  s += __shfl_xor(s, 2);
  s += __shfl_xor(s, 4);
  s += __shfl_xor(s, 8);
  float contrib = (jt == 0) ? LN2 * (LOG2F(s) - g2[row]) : 0.f;
  contrib += __shfl_xor(contrib, 16);
  contrib += __shfl_xor(contrib, 32);
  __shared__ float red[4];
  if ((tid & 63) == 0) red[tid >> 6] = contrib;
  __syncthreads();
  if (tid == 0) {
    float blocksum = red[0] + red[1] + red[2] + red[3];
    atomicAdd(out, blocksum * (1.0f / 2048.0f));
  }
}

// ---------------- launch ----------------------------------------------------
extern "C" void kernel_launch(void* const* d_in, const int* in_sizes, int n_in,
                              void* d_out, int out_size, void* d_ws, size_t ws_size,
                              hipStream_t stream)
{
  // inputs: 0=pred (UNUSED), 1=unc, 2=y, 3=features, 4=classifier_weight
  const float* unc  = (const float*)d_in[1];
  const int*   yin  = (const int*)d_in[2];
  const float* feat = (const float*)d_in[3];
  const float* W    = (const float*)d_in[4];
  const int B = in_sizes[1];            // 2048
  const int D = 128;
  const int C = in_sizes[4] / D;        // 16384

  char* ws = (char*)d_ws;
  size_t off = 0;
  auto alloc = [&](size_t bytes) -> void* {
    void* p = ws + off;
    off += (bytes + 255) & ~(size_t)255;
    return p;
  };
  bf16*  swF     = (bf16*)alloc((size_t)B * D * sizeof(bf16));
  float* k1v     = (float*)alloc((size_t)B * 4);
  float* g2      = (float*)alloc((size_t)B * 4);
  float* partial = (float*)alloc((size_t)1024 * 2048 * 4);   // 8 MB

  vmf_prepF<<<(B + 3) / 4, 256, 0, stream>>>(feat, unc, swF, k1v,
                                             (float*)d_out, B);
  dim3 g1(C / 64, 4);                   // 256 x 4 = 1024 blocks, 4/CU
  vmf_main<<<g1, 256, 0, stream>>>(W, swF, k1v, yin, partial, g2);
  vmf_finish<<<128, 256, 0, stream>>>(partial, g2, (float*)d_out);
}

// Round 7
// 209.557 us; speedup vs baseline: 1.0175x; 1.0175x over previous
//
#include <hip/hip_runtime.h>
#include <hip/hip_bf16.h>

// vMF expected-likelihood loss, MI355X gfx950. Shapes hardcoded: B=2048,
// C=16384, D=128.
// prepF: normalize FEATURE rows -> bf16 fragment-swizzled swF, k1=1/unc,
//        zero d_out accumulator.
// main:  grid (C/64=256, 4). Block OWNS 64 classes: normalizes fp32 W rows
//        in-kernel -> register-resident A-fragments + per-class consts.
//        Batch loop: 16 chunks x 32 rows; each chunk's 8 KB of B-fragments is
//        staged into LDS ONCE per block (cooperative copy, double-buffered,
//        1 barrier/chunk) and shared by all 4 waves via ds_read_b128 --
//        cuts L2 fragment traffic 4x (512->128 MB), which was the R4-R6
//        bottleneck. Then 8 MFMA -> packed-f32 poly epilogue -> fixed-shift
//        sum of exp2 -> quad-fold -> coalesced store to private partial row.
// finish: 128 blocks reduce partial[1024][2048], row loss =
//        ln2*(log2(sum)-z_y), block-reduce, one atomicAdd per block.
//
// Math: f(kappa)=63*ln(63+s)+0.5*ln(s)-s, s=sqrt(63^2+kappa^2); per-row f(k1)
// and all additive constants cancel in (-gathered + lse). F(s)=
// 63*log2(63+s)+0.5*log2(s)-log2e*s approx on s in [85,185] by deg-4 poly in
// t=0.02s-2.7 (max err ~1.4e-2 log2 => ~0.01 nats; threshold 0.195).
// |z| bounded (~40) so fp32 Sum exp2(z) cannot overflow: no max tracking.

typedef __bf16 bf16;
typedef __attribute__((ext_vector_type(8))) __bf16 bf16x8;
typedef __attribute__((ext_vector_type(4))) float f32x4;
typedef __attribute__((ext_vector_type(2))) float f32x2;

#define LOG2E 1.44269504088896340736f
#define LN2   0.69314718055994530942f
#define VNU   63.0f
#define VSQ   3969.0f

#if __has_builtin(__builtin_amdgcn_exp2f)
#define EXP2F(x) __builtin_amdgcn_exp2f(x)
#else
#define EXP2F(x) exp2f(x)
#endif
#if __has_builtin(__builtin_amdgcn_sqrtf)
#define SQRTF(x) __builtin_amdgcn_sqrtf(x)
#else
#define SQRTF(x) sqrtf(x)
#endif
#if __has_builtin(__builtin_amdgcn_logf)   /* v_log_f32 = log2 */
#define LOG2F(x) __builtin_amdgcn_logf(x)
#else
#define LOG2F(x) __log2f(x)
#endif

// F(s) poly in t = 0.02*s - 2.7 (deg 4)
#define QC0  289.4379f
#define QC1  -48.9193f
#define QC2  -2.9400f
#define QC3  0.51653f
#define QC4  -0.11373f

// ---------------- prepF: features + k1 + zero out ---------------------------
__global__ __launch_bounds__(256) void vmf_prepF(
    const float* __restrict__ feat, const float* __restrict__ unc,
    bf16* __restrict__ swF, float* __restrict__ k1,
    float* __restrict__ out0, int B)
{
  if (blockIdx.x == 0 && threadIdx.x == 0) out0[0] = 0.0f;
  const int lane = threadIdx.x & 63;
  const int b    = blockIdx.x * 4 + (threadIdx.x >> 6);
  if (b >= B) return;
  float2 xv = reinterpret_cast<const float2*>(feat + (size_t)b * 128)[lane];
  float ssq = fmaf(xv.x, xv.x, xv.y * xv.y);
  #pragma unroll
  for (int off = 32; off; off >>= 1) ssq += __shfl_xor(ssq, off);
  float inv = 1.0f / fmaxf(sqrtf(ssq), 1e-12f);
  __hip_bfloat162 hv = __float22bfloat162_rn(make_float2(xv.x * inv, xv.y * inv));
  // fragment swizzle: lane holds elements d = 2*lane, 2*lane+1
  const int t   = b >> 4;
  const int l15 = b & 15;
  const int kk  = lane >> 4;
  const int qq  = (lane >> 2) & 3;
  const int j   = 2 * (lane & 3);
  const size_t eoff = (((size_t)(t * 4 + kk)) * 64 + qq * 16 + l15) * 8 + j;
  *reinterpret_cast<__hip_bfloat162*>(swF + eoff) = hv;
  if (lane == 0) k1[b] = 1.0f / unc[b];
}

// ---------------- main ------------------------------------------------------
__global__ __launch_bounds__(256, 4) void vmf_main(
    const float* __restrict__ W, const bf16* __restrict__ swF,
    const float* __restrict__ k1a, const int* __restrict__ yy,
    float* __restrict__ partial, float* __restrict__ g2)
{
  // union: class-prep staging (16 KB, prologue only) | B double buffer (2x8KB)
  __shared__ bf16   ldsU[8192];
  __shared__ float4 ldsC[64];        // per-class consts {2k2, k2^2+VSQ, f2l}

  const int lane = threadIdx.x & 63;
  const int wave = threadIdx.x >> 6;
  const int q    = lane >> 4;
  const int l15  = lane & 15;
  const int bx   = blockIdx.x;

  // ---- one-time in-kernel class prep: 16 classes/wave, 1 row per 4 lanes --
  {
    const int r16 = lane >> 2;
    const int p   = lane & 3;
    const int gc  = bx * 64 + wave * 16 + r16;
    const float4* wp = reinterpret_cast<const float4*>(W + (size_t)gc * 128 + p * 32);
    float4 xv[8];
    float ssq = 0.f;
    #pragma unroll
    for (int i = 0; i < 8; ++i) {
      xv[i] = wp[i];
      ssq += xv[i].x * xv[i].x + xv[i].y * xv[i].y +
             xv[i].z * xv[i].z + xv[i].w * xv[i].w;
    }
    ssq += __shfl_xor(ssq, 1);
    ssq += __shfl_xor(ssq, 2);
    float norm = sqrtf(ssq);
    float inv  = 1.0f / fmaxf(norm, 1e-12f);
    #pragma unroll
    for (int q2 = 0; q2 < 4; ++q2) {
      float4 a = xv[2 * q2], c = xv[2 * q2 + 1];
      __hip_bfloat162 h[4] = {
        __float22bfloat162_rn(make_float2(a.x * inv, a.y * inv)),
        __float22bfloat162_rn(make_float2(a.z * inv, a.w * inv)),
        __float22bfloat162_rn(make_float2(c.x * inv, c.y * inv)),
        __float22bfloat162_rn(make_float2(c.z * inv, c.w * inv))};
      *reinterpret_cast<bf16x8*>(&ldsU[wave * 2048 + (p * 64 + q2 * 16 + r16) * 8]) =
          *reinterpret_cast<bf16x8*>(h);
    }
    if (p == 0) {
      float kap = fmaxf(norm, 1.0f) * 10.0f;
      float s2  = sqrtf(fmaf(kap, kap, VSQ));
      float f2l = fmaf(VNU, LOG2F(VNU + s2), 0.5f * LOG2F(s2)) - LOG2E * s2;
      ldsC[wave * 16 + r16] = make_float4(2.0f * kap, fmaf(kap, kap, VSQ), f2l, 0.0f);
    }
  }
  __syncthreads();

  // register-resident A fragments + class consts
  bf16x8 af[4];
  #pragma unroll
  for (int kk = 0; kk < 4; ++kk)
    af[kk] = *reinterpret_cast<bf16x8*>(&ldsU[wave * 2048 + (kk * 64 + lane) * 8]);
  const int cls_base = bx * 64 + wave * 16 + q * 4;
  f32x2 cvx[4], cvy[4], cvz[4];
  #pragma unroll
  for (int r = 0; r < 4; ++r) {
    float4 c = ldsC[wave * 16 + q * 4 + r];
    cvx[r] = (f32x2){c.x, c.x};
    cvy[r] = (f32x2){c.y, c.y};
    cvz[r] = (f32x2){c.z, c.z};
  }
  __syncthreads();   // af/consts consumed (lgkm drained) -> ldsU reusable as B dbuf

  // ---- batch loop: 16 chunks x 32 rows, B staged in LDS double buffer -----
  // chunk ch occupies ldsU[(ch&1)*4096 .. +4096) (2 row-tiles x 2048 elems).
  const int rowbase = (int)blockIdx.y << 9;          // NR = 512
  const int pbase   = (bx * 4 + wave) * 2048;        // private partial row
  const int tid     = threadIdx.x;

  // stage chunk 0: 256 threads x 16 elements (8 per row-tile), coalesced
  {
    const size_t src0 = ((size_t)(rowbase >> 4)) * 2048 + tid * 8;
    bf16x8 t0 = *reinterpret_cast<const bf16x8*>(swF + src0);
    bf16x8 t1 = *reinterpret_cast<const bf16x8*>(swF + src0 + 2048);
    *reinterpret_cast<bf16x8*>(&ldsU[tid * 8])        = t0;
    *reinterpret_cast<bf16x8*>(&ldsU[2048 + tid * 8]) = t1;
  }

  for (int ch = 0; ch < 16; ++ch) {
    __syncthreads();                         // buf[ch&1] staged & visible
    const int bufo = (ch & 1) * 4096;
    // B fragments from LDS (shared by all 4 waves)
    bf16x8 bfr[2][4];
    #pragma unroll
    for (int tl = 0; tl < 2; ++tl)
      #pragma unroll
      for (int kk = 0; kk < 4; ++kk)
        bfr[tl][kk] = *reinterpret_cast<bf16x8*>(
            &ldsU[bufo + tl * 2048 + (kk * 64 + lane) * 8]);

    const int row0 = rowbase + ch * 32 + l15;
    const float k10 = k1a[row0], k11 = k1a[row0 + 16];
    const int   yv0 = yy[row0],  yv1 = yy[row0 + 16];

    // issue next chunk's global loads early (ds_write after compute)
    bf16x8 t0, t1;
    if (ch < 15) {
      const size_t srcn = ((size_t)(rowbase >> 4) + (ch + 1) * 2) * 2048 + tid * 8;
      t0 = *reinterpret_cast<const bf16x8*>(swF + srcn);
      t1 = *reinterpret_cast<const bf16x8*>(swF + srcn + 2048);
    }

    f32x4 acc0 = {0.f, 0.f, 0.f, 0.f};
    f32x4 acc1 = {0.f, 0.f, 0.f, 0.f};
    #pragma unroll
    for (int kk = 0; kk < 4; ++kk) {
      acc0 = __builtin_amdgcn_mfma_f32_16x16x32_bf16(af[kk], bfr[0][kk], acc0, 0, 0, 0);
      acc1 = __builtin_amdgcn_mfma_f32_16x16x32_bf16(af[kk], bfr[1][kk], acc1, 0, 0, 0);
    }

    const f32x2 k1pk   = {k10, k11};
    const f32x2 k1sqpk = k1pk * k1pk;
    f32x2 z[4];
    f32x2 sum = {0.f, 0.f};
    #pragma unroll
    for (int r = 0; r < 4; ++r) {
      f32x2 acc2 = {acc0[r], acc1[r]};
      f32x2 u = __builtin_elementwise_fma(cvx[r] * k1pk, acc2, k1sqpk + cvy[r]);
      u = __builtin_elementwise_max(u, (f32x2){VSQ, VSQ});
      f32x2 s3 = {SQRTF(u.x), SQRTF(u.y)};
      f32x2 t  = __builtin_elementwise_fma((f32x2){0.02f, 0.02f}, s3,
                                           (f32x2){-2.7f, -2.7f});
      f32x2 p  = __builtin_elementwise_fma(t, (f32x2){QC4, QC4}, (f32x2){QC3, QC3});
      p = __builtin_elementwise_fma(t, p, (f32x2){QC2, QC2});
      p = __builtin_elementwise_fma(t, p, (f32x2){QC1, QC1});
      p = __builtin_elementwise_fma(t, p, (f32x2){QC0, QC0});
      z[r] = cvz[r] - p;
      sum += (f32x2){EXP2F(z[r].x), EXP2F(z[r].y)};
    }
    // gathered term: exactly one (bx, wave, q, r) matches per row
    if ((yv0 & ~3) == cls_base) {
      int rr = yv0 - cls_base;
      float zz = rr == 0 ? z[0].x : rr == 1 ? z[1].x : rr == 2 ? z[2].x : z[3].x;
      g2[row0] = zz;
    }
    if ((yv1 & ~3) == cls_base) {
      int rr = yv1 - cls_base;
      float zz = rr == 0 ? z[0].y : rr == 1 ? z[1].y : rr == 2 ? z[2].y : z[3].y;
      g2[row0 + 16] = zz;
    }
    // fold quads (16 classes) -> per-row partial; direct coalesced store
    sum.x += __shfl_xor(sum.x, 16); sum.x += __shfl_xor(sum.x, 32);
    sum.y += __shfl_xor(sum.y, 16); sum.y += __shfl_xor(sum.y, 32);
    if (q == 0) {
      partial[pbase + row0]      = sum.x;
      partial[pbase + row0 + 16] = sum.y;
    }
    // ds_write the prefetched chunk (loads have had the whole epilogue to land)
    if (ch < 15) {
      const int nbufo = ((ch + 1) & 1) * 4096;
      *reinterpret_cast<bf16x8*>(&ldsU[nbufo + tid * 8])        = t0;
      *reinterpret_cast<bf16x8*>(&ldsU[nbufo + 2048 + tid * 8]) = t1;
    }
  }
}

// ---------------- finish: reduce partial matrix -> mean loss ----------------
// grid 128 blocks x 256 threads; block owns 16 rows; thread = rl*16 + jt.
__global__ __launch_bounds__(256) void vmf_finish(
    const float* __restrict__ partial, const float* __restrict__ g2,
    float* __restrict__ out)
{
  const int tid = threadIdx.x;
  const int jt  = tid & 15;
  const int rl  = tid >> 4;
  const int row = blockIdx.x * 16 + rl;
  float s = 0.f;
  #pragma unroll 8
  for (int i = 0; i < 64; ++i)
    s += partial[(size_t)(jt + 16 * i) * 2048 + row];
  s += __shfl_xor(s, 1);
  s += __shfl_xor(s, 2);
  s += __shfl_xor(s, 4);
  s += __shfl_xor(s, 8);
  float contrib = (jt == 0) ? LN2 * (LOG2F(s) - g2[row]) : 0.f;
  contrib += __shfl_xor(contrib, 16);
  contrib += __shfl_xor(contrib, 32);
  __shared__ float red[4];
  if ((tid & 63) == 0) red[tid >> 6] = contrib;
  __syncthreads();
  if (tid == 0) {
    float blocksum = red[0] + red[1] + red[2] + red[3];
    atomicAdd(out, blocksum * (1.0f / 2048.0f));
  }
}

// ---------------- launch ----------------------------------------------------
extern "C" void kernel_launch(void* const* d_in, const int* in_sizes, int n_in,
                              void* d_out, int out_size, void* d_ws, size_t ws_size,
                              hipStream_t stream)
{
  // inputs: 0=pred (UNUSED), 1=unc, 2=y, 3=features, 4=classifier_weight
  const float* unc  = (const float*)d_in[1];
  const int*   yin  = (const int*)d_in[2];
  const float* feat = (const float*)d_in[3];
  const float* W    = (const float*)d_in[4];
  const int B = in_sizes[1];            // 2048
  const int D = 128;
  const int C = in_sizes[4] / D;        // 16384

  char* ws = (char*)d_ws;
  size_t off = 0;
  auto alloc = [&](size_t bytes) -> void* {
    void* p = ws + off;
    off += (bytes + 255) & ~(size_t)255;
    return p;
  };
  bf16*  swF     = (bf16*)alloc((size_t)B * D * sizeof(bf16));
  float* k1v     = (float*)alloc((size_t)B * 4);
  float* g2      = (float*)alloc((size_t)B * 4);
  float* partial = (float*)alloc((size_t)1024 * 2048 * 4);   // 8 MB

  vmf_prepF<<<(B + 3) / 4, 256, 0, stream>>>(feat, unc, swF, k1v,
                                             (float*)d_out, B);
  dim3 g1(C / 64, 4);                   // 256 x 4 = 1024 blocks, 4/CU
  vmf_main<<<g1, 256, 0, stream>>>(W, swF, k1v, yin, partial, g2);
  vmf_finish<<<128, 256, 0, stream>>>(partial, g2, (float*)d_out);
}

// Round 8
// 207.979 us; speedup vs baseline: 1.0252x; 1.0076x over previous
//
#include <hip/hip_runtime.h>
#include <hip/hip_bf16.h>

// vMF expected-likelihood loss, MI355X gfx950. Shapes hardcoded: B=2048,
// C=16384, D=128.
// prep:  normalize ALL rows (W then features) -> bf16 fragment-swizzled
//        swW/swF, per-class consts {2k2, k2^2+v^2, f2*log2e}, k1=1/unc,
//        zero d_out. Fully parallel, one-time; removes the serial W-prologue
//        that headed every main block in R5-R7 (4x redundant W read+normalize).
// main:  grid (C/64=256, 4). Block owns 64 classes: ONE coalesced A-fragment
//        load per wave (4 KB from swW, L2) + 16 cst reads -> register-resident
//        for the whole kernel. Batch loop: 16 chunks x 32 rows; each chunk's
//        8 KB of B-fragments staged into LDS once per block (double-buffered,
//        1 barrier/chunk, shared by all 4 waves) -> 8 MFMA -> packed-f32 poly
//        epilogue -> fixed-shift sum of exp2 -> quad-fold -> coalesced store
//        to private partial row (no atomics in the loop).
// finish: 128 blocks reduce partial[1024][2048], row loss =
//        ln2*(log2(sum)-z_y), block-reduce, one atomicAdd per block.
//
// Math: f(kappa)=63*ln(63+s)+0.5*ln(s)-s, s=sqrt(63^2+kappa^2); per-row f(k1)
// and all additive constants cancel in (-gathered + lse). F(s)=
// 63*log2(63+s)+0.5*log2(s)-log2e*s approx on s in [85,185] by deg-4 poly in
// t=0.02s-2.7 (max err ~1.4e-2 log2 => ~0.01 nats; threshold 0.195).
// |z| bounded (~40) so fp32 Sum exp2(z) cannot overflow: no max tracking.

typedef __bf16 bf16;
typedef __attribute__((ext_vector_type(8))) __bf16 bf16x8;
typedef __attribute__((ext_vector_type(4))) float f32x4;
typedef __attribute__((ext_vector_type(2))) float f32x2;

#define LOG2E 1.44269504088896340736f
#define LN2   0.69314718055994530942f
#define VNU   63.0f
#define VSQ   3969.0f

#if __has_builtin(__builtin_amdgcn_exp2f)
#define EXP2F(x) __builtin_amdgcn_exp2f(x)
#else
#define EXP2F(x) exp2f(x)
#endif
#if __has_builtin(__builtin_amdgcn_sqrtf)
#define SQRTF(x) __builtin_amdgcn_sqrtf(x)
#else
#define SQRTF(x) sqrtf(x)
#endif
#if __has_builtin(__builtin_amdgcn_logf)   /* v_log_f32 = log2 */
#define LOG2F(x) __builtin_amdgcn_logf(x)
#else
#define LOG2F(x) __log2f(x)
#endif

// F(s) poly in t = 0.02*s - 2.7 (deg 4)
#define QC0  289.4379f
#define QC1  -48.9193f
#define QC2  -2.9400f
#define QC3  0.51653f
#define QC4  -0.11373f

// ---------------- prep: W + features, swizzle, consts, k1, zero out ---------
__global__ __launch_bounds__(256) void vmf_prep(
    const float* __restrict__ W, const float* __restrict__ feat,
    const float* __restrict__ unc,
    bf16* __restrict__ swW, bf16* __restrict__ swF,
    float4* __restrict__ cst, float* __restrict__ k1,
    float* __restrict__ out0, int C, int B)
{
  if (blockIdx.x == 0 && threadIdx.x == 0) out0[0] = 0.0f;
  const int lane = threadIdx.x & 63;
  const int idx  = blockIdx.x * 4 + (threadIdx.x >> 6);
  const bool is_class = idx < C;
  const int b = idx - C;
  const float* src;
  bf16* dstbase;
  int r;
  if (is_class) { src = W + (size_t)idx * 128;  dstbase = swW;  r = idx; }
  else {
    if (b >= B) return;
    src = feat + (size_t)b * 128;  dstbase = swF;  r = b;
  }
  float2 xv = reinterpret_cast<const float2*>(src)[lane];
  float ssq = fmaf(xv.x, xv.x, xv.y * xv.y);
  #pragma unroll
  for (int off = 32; off; off >>= 1) ssq += __shfl_xor(ssq, off);
  float norm = sqrtf(ssq);
  float inv  = 1.0f / fmaxf(norm, 1e-12f);
  __hip_bfloat162 hv = __float22bfloat162_rn(make_float2(xv.x * inv, xv.y * inv));
  // fragment swizzle: lane holds elements d = 2*lane, 2*lane+1
  const int t   = r >> 4;
  const int l15 = r & 15;
  const int kk  = lane >> 4;
  const int qq  = (lane >> 2) & 3;
  const int j   = 2 * (lane & 3);
  const size_t eoff = (((size_t)(t * 4 + kk)) * 64 + qq * 16 + l15) * 8 + j;
  *reinterpret_cast<__hip_bfloat162*>(dstbase + eoff) = hv;
  if (lane == 0) {
    if (is_class) {
      float kap = fmaxf(norm, 1.0f) * 10.0f;
      float s2  = sqrtf(fmaf(kap, kap, VSQ));
      float f2l = fmaf(VNU, LOG2F(VNU + s2), 0.5f * LOG2F(s2)) - LOG2E * s2;
      cst[idx] = make_float4(2.0f * kap, fmaf(kap, kap, VSQ), f2l, 0.0f);
    } else {
      k1[b] = 1.0f / unc[b];
    }
  }
}

// ---------------- main ------------------------------------------------------
__global__ __launch_bounds__(256, 4) void vmf_main(
    const bf16* __restrict__ swW, const bf16* __restrict__ swF,
    const float4* __restrict__ cst, const float* __restrict__ k1a,
    const int* __restrict__ yy, float* __restrict__ partial,
    float* __restrict__ g2)
{
  __shared__ bf16 ldsB[8192];        // B double buffer: 2 x 4096 elems (8 KB)

  const int lane = threadIdx.x & 63;
  const int wave = threadIdx.x >> 6;
  const int q    = lane >> 4;
  const int l15  = lane & 15;
  const int bx   = blockIdx.x;
  const int tid  = threadIdx.x;

  // one-time A fragments (this wave's 16 classes), coalesced from swW
  const int t = bx * 4 + wave;
  bf16x8 af[4];
  #pragma unroll
  for (int kk = 0; kk < 4; ++kk)
    af[kk] = *reinterpret_cast<const bf16x8*>(
        swW + (((size_t)t * 4 + kk) * 64 + lane) * 8);
  // one-time class consts (broadcast within quad)
  const int cls_base = bx * 64 + wave * 16 + q * 4;
  f32x2 cvx[4], cvy[4], cvz[4];
  #pragma unroll
  for (int r = 0; r < 4; ++r) {
    float4 c = cst[cls_base + r];
    cvx[r] = (f32x2){c.x, c.x};
    cvy[r] = (f32x2){c.y, c.y};
    cvz[r] = (f32x2){c.z, c.z};
  }

  // ---- batch loop: 16 chunks x 32 rows, B staged in LDS double buffer -----
  const int rowbase = (int)blockIdx.y << 9;          // NR = 512
  const int pbase   = (bx * 4 + wave) * 2048;        // private partial row

  // stage chunk 0: 256 threads x 16 elems (8 per row-tile), coalesced
  {
    const size_t src0 = ((size_t)(rowbase >> 4)) * 2048 + tid * 8;
    bf16x8 t0 = *reinterpret_cast<const bf16x8*>(swF + src0);
    bf16x8 t1 = *reinterpret_cast<const bf16x8*>(swF + src0 + 2048);
    *reinterpret_cast<bf16x8*>(&ldsB[tid * 8])        = t0;
    *reinterpret_cast<bf16x8*>(&ldsB[2048 + tid * 8]) = t1;
  }

  for (int ch = 0; ch < 16; ++ch) {
    __syncthreads();                         // buf[ch&1] staged & visible
    const int bufo = (ch & 1) * 4096;
    bf16x8 bfr[2][4];
    #pragma unroll
    for (int tl = 0; tl < 2; ++tl)
      #pragma unroll
      for (int kk = 0; kk < 4; ++kk)
        bfr[tl][kk] = *reinterpret_cast<bf16x8*>(
            &ldsB[bufo + tl * 2048 + (kk * 64 + lane) * 8]);

    const int row0 = rowbase + ch * 32 + l15;
    const float k10 = k1a[row0], k11 = k1a[row0 + 16];
    const int   yv0 = yy[row0],  yv1 = yy[row0 + 16];

    // issue next chunk's global loads early (ds_write after compute)
    bf16x8 t0, t1;
    if (ch < 15) {
      const size_t srcn = ((size_t)(rowbase >> 4) + (ch + 1) * 2) * 2048 + tid * 8;
      t0 = *reinterpret_cast<const bf16x8*>(swF + srcn);
      t1 = *reinterpret_cast<const bf16x8*>(swF + srcn + 2048);
    }

    f32x4 acc0 = {0.f, 0.f, 0.f, 0.f};
    f32x4 acc1 = {0.f, 0.f, 0.f, 0.f};
    #pragma unroll
    for (int kk = 0; kk < 4; ++kk) {
      acc0 = __builtin_amdgcn_mfma_f32_16x16x32_bf16(af[kk], bfr[0][kk], acc0, 0, 0, 0);
      acc1 = __builtin_amdgcn_mfma_f32_16x16x32_bf16(af[kk], bfr[1][kk], acc1, 0, 0, 0);
    }

    const f32x2 k1pk   = {k10, k11};
    const f32x2 k1sqpk = k1pk * k1pk;
    f32x2 z[4];
    f32x2 sum = {0.f, 0.f};
    #pragma unroll
    for (int r = 0; r < 4; ++r) {
      f32x2 acc2 = {acc0[r], acc1[r]};
      f32x2 u = __builtin_elementwise_fma(cvx[r] * k1pk, acc2, k1sqpk + cvy[r]);
      u = __builtin_elementwise_max(u, (f32x2){VSQ, VSQ});
      f32x2 s3 = {SQRTF(u.x), SQRTF(u.y)};
      f32x2 tt = __builtin_elementwise_fma((f32x2){0.02f, 0.02f}, s3,
                                           (f32x2){-2.7f, -2.7f});
      f32x2 p  = __builtin_elementwise_fma(tt, (f32x2){QC4, QC4}, (f32x2){QC3, QC3});
      p = __builtin_elementwise_fma(tt, p, (f32x2){QC2, QC2});
      p = __builtin_elementwise_fma(tt, p, (f32x2){QC1, QC1});
      p = __builtin_elementwise_fma(tt, p, (f32x2){QC0, QC0});
      z[r] = cvz[r] - p;
      sum += (f32x2){EXP2F(z[r].x), EXP2F(z[r].y)};
    }
    // gathered term: exactly one (bx, wave, q, r) matches per row
    if ((yv0 & ~3) == cls_base) {
      int rr = yv0 - cls_base;
      float zz = rr == 0 ? z[0].x : rr == 1 ? z[1].x : rr == 2 ? z[2].x : z[3].x;
      g2[row0] = zz;
    }
    if ((yv1 & ~3) == cls_base) {
      int rr = yv1 - cls_base;
      float zz = rr == 0 ? z[0].y : rr == 1 ? z[1].y : rr == 2 ? z[2].y : z[3].y;
      g2[row0 + 16] = zz;
    }
    // fold quads (16 classes) -> per-row partial; direct coalesced store
    sum.x += __shfl_xor(sum.x, 16); sum.x += __shfl_xor(sum.x, 32);
    sum.y += __shfl_xor(sum.y, 16); sum.y += __shfl_xor(sum.y, 32);
    if (q == 0) {
      partial[pbase + row0]      = sum.x;
      partial[pbase + row0 + 16] = sum.y;
    }
    // ds_write the prefetched chunk (loads had the whole epilogue to land)
    if (ch < 15) {
      const int nbufo = ((ch + 1) & 1) * 4096;
      *reinterpret_cast<bf16x8*>(&ldsB[nbufo + tid * 8])        = t0;
      *reinterpret_cast<bf16x8*>(&ldsB[nbufo + 2048 + tid * 8]) = t1;
    }
  }
}

// ---------------- finish: reduce partial matrix -> mean loss ----------------
// grid 128 blocks x 256 threads; block owns 16 rows; thread = rl*16 + jt.
__global__ __launch_bounds__(256) void vmf_finish(
    const float* __restrict__ partial, const float* __restrict__ g2,
    float* __restrict__ out)
{
  const int tid = threadIdx.x;
  const int jt  = tid & 15;
  const int rl  = tid >> 4;
  const int row = blockIdx.x * 16 + rl;
  float s = 0.f;
  #pragma unroll 8
  for (int i = 0; i < 64; ++i)
    s += partial[(size_t)(jt + 16 * i) * 2048 + row];
  s += __shfl_xor(s, 1);
  s += __shfl_xor(s, 2);
  s += __shfl_xor(s, 4);
  s += __shfl_xor(s, 8);
  float contrib = (jt == 0) ? LN2 * (LOG2F(s) - g2[row]) : 0.f;
  contrib += __shfl_xor(contrib, 16);
  contrib += __shfl_xor(contrib, 32);
  __shared__ float red[4];
  if ((tid & 63) == 0) red[tid >> 6] = contrib;
  __syncthreads();
  if (tid == 0) {
    float blocksum = red[0] + red[1] + red[2] + red[3];
    atomicAdd(out, blocksum * (1.0f / 2048.0f));
  }
}

// ---------------- launch ----------------------------------------------------
extern "C" void kernel_launch(void* const* d_in, const int* in_sizes, int n_in,
                              void* d_out, int out_size, void* d_ws, size_t ws_size,
                              hipStream_t stream)
{
  // inputs: 0=pred (UNUSED), 1=unc, 2=y, 3=features, 4=classifier_weight
  const float* unc  = (const float*)d_in[1];
  const int*   yin  = (const int*)d_in[2];
  const float* feat = (const float*)d_in[3];
  const float* W    = (const float*)d_in[4];
  const int B = in_sizes[1];            // 2048
  const int D = 128;
  const int C = in_sizes[4] / D;        // 16384

  char* ws = (char*)d_ws;
  size_t off = 0;
  auto alloc = [&](size_t bytes) -> void* {
    void* p = ws + off;
    off += (bytes + 255) & ~(size_t)255;
    return p;
  };
  bf16*   swW     = (bf16*)alloc((size_t)C * D * sizeof(bf16));
  bf16*   swF     = (bf16*)alloc((size_t)B * D * sizeof(bf16));
  float4* cstv    = (float4*)alloc((size_t)C * sizeof(float4));
  float*  k1v     = (float*)alloc((size_t)B * 4);
  float*  g2      = (float*)alloc((size_t)B * 4);
  float*  partial = (float*)alloc((size_t)1024 * 2048 * 4);   // 8 MB

  vmf_prep<<<(C + B + 3) / 4, 256, 0, stream>>>(W, feat, unc, swW, swF,
                                                cstv, k1v, (float*)d_out, C, B);
  dim3 g1(C / 64, 4);                   // 256 x 4 = 1024 blocks, 4/CU
  vmf_main<<<g1, 256, 0, stream>>>(swW, swF, cstv, k1v, yin, partial, g2);
  vmf_finish<<<128, 256, 0, stream>>>(partial, g2, (float*)d_out);
}